// Round 8
// baseline (29852.774 us; speedup 1.0000x reference)
//
#include <hip/hip_runtime.h>

// DA-RNN decoder: B=512, T=128, E=256, D=256, OUT=1.
// R8: R6 base (one 1024-thread block per CU, NB=2 rows, lockstep phases,
// ep slice in LDS) + explicit chunked register double-buffer for the phase-A
// weight stream (the binding resource: 768 KB/CU/step from L2; R6's 52 VGPRs
// meant latency-bound loads). Chunk=4 iters, prefetch next chunk while
// computing current; chunk 0 of step t+1 prefetched at end of step t.
// Phases C+D merged (redundant all-wave shfl softmax) -> 3 barriers/step.

#define BB 512
#define TT 128
#define EE 256
#define DD 256
#define NB 2
#define NTHR 1024

typedef _Float16 h2 __attribute__((ext_vector_type(2)));
typedef _Float16 h8 __attribute__((ext_vector_type(8)));

#if defined(__has_builtin)
#if __has_builtin(__builtin_amdgcn_fdot2)
#define HAS_FDOT2 1
#endif
#endif

#ifdef HAS_FDOT2
#define FDOT2(a, b, c) __builtin_amdgcn_fdot2(__builtin_bit_cast(h2, (a)), __builtin_bit_cast(h2, (b)), (c), false)
#else
static __device__ __forceinline__ float FDOT2(unsigned int a, unsigned int b, float c) {
    h2 x = __builtin_bit_cast(h2, a), y = __builtin_bit_cast(h2, b);
    return c + (float)x[0] * (float)y[0] + (float)x[1] * (float)y[1];
}
#endif

static __device__ __forceinline__ float dot8u4(uint4 w, uint4 h, float acc) {
    acc = FDOT2(w.x, h.x, acc);
    acc = FDOT2(w.y, h.y, acc);
    acc = FDOT2(w.z, h.z, acc);
    acc = FDOT2(w.w, h.w, acc);
    return acc;
}
static __device__ __forceinline__ unsigned int pkh(float a, float b) {
    union { _Float16 h; unsigned short s; } ua, ub;
    ua.h = (_Float16)a; ub.h = (_Float16)b;
    return (unsigned int)ua.s | ((unsigned int)ub.s << 16);
}
__device__ __forceinline__ float ftanh(float x) {
    return 1.f - 2.f * __builtin_amdgcn_rcpf(__expf(2.f * x) + 1.f);
}
__device__ __forceinline__ float fsig(float x) {
    return __builtin_amdgcn_rcpf(1.f + __expf(-x));
}

// Pack weights to f16 in the exact load order of k_main.
// aW1h[(g*256+f)*8+j] = aW1[g*8+j][f]      (g = kh*32+i < 64, k=g*8+j < 512)
// WhhH[(i*1024+jj)*8+m] = Whh[jj][i*8+m]   (i<32)
__global__ __launch_bounds__(256) void k_pack(const float* __restrict__ aW1,
                                              const float* __restrict__ Whh,
                                              const float* __restrict__ bih,
                                              const float* __restrict__ bhh,
                                              _Float16* __restrict__ aW1h,
                                              _Float16* __restrict__ WhhH,
                                              float* __restrict__ bias) {
    int bid = blockIdx.x, tid = threadIdx.x;
    if (bid < 512) {
        int o = bid * 256 + tid;                 // < 131072
        int g = o >> 11, f = (o >> 3) & 255, j = o & 7;
        aW1h[o] = (_Float16)aW1[(g * 8 + j) * EE + f];
    } else if (bid < 1536) {
        int o = (bid - 512) * 256 + tid;         // < 262144
        int i = o >> 13, jj = (o >> 3) & 1023, m = o & 7;
        WhhH[o] = (_Float16)Whh[jj * DD + i * 8 + m];
    } else {
        int j = (bid - 1536) * 256 + tid;        // < 1024
        bias[j] = bih[j] + bhh[j];
    }
}

// ep[n][f] = f16( sum_e ie[n][e]*aW1[512+e][f] )
// epilogue: iefc[n] = dot(ie[n], fcW[0:256]); ieff[n] = dot(ie[n], ffW[256:512])
__global__ __launch_bounds__(256) void k_encproj(const float* __restrict__ ie,
                                                 const float* __restrict__ aW1,
                                                 const float* __restrict__ fcW,
                                                 const float* __restrict__ ffW,
                                                 _Float16* __restrict__ ep,
                                                 float* __restrict__ iefc,
                                                 float* __restrict__ ieff) {
    __shared__ float a[32][EE];
    int row0 = blockIdx.x * 32;
    int tid = threadIdx.x;
    for (int r = 0; r < 32; ++r)
        a[r][tid] = ie[(size_t)(row0 + r) * EE + tid];
    __syncthreads();
    float acc[32];
    #pragma unroll
    for (int r = 0; r < 32; ++r) acc[r] = 0.f;
    const float* wenc = aW1 + 512 * EE;
    for (int e = 0; e < EE; e += 4) {
        float w0 = wenc[(e + 0) * EE + tid];
        float w1 = wenc[(e + 1) * EE + tid];
        float w2 = wenc[(e + 2) * EE + tid];
        float w3 = wenc[(e + 3) * EE + tid];
        #pragma unroll
        for (int r = 0; r < 32; ++r) {
            float4 av = *(const float4*)&a[r][e];
            acc[r] += av.x * w0 + av.y * w1 + av.z * w2 + av.w * w3;
        }
    }
    for (int r = 0; r < 32; ++r)
        ep[(size_t)(row0 + r) * EE + tid] = (_Float16)acc[r];

    int wave = tid >> 6, lane = tid & 63;
    float4 f1 = *(const float4*)&fcW[lane * 4];
    float4 f2 = *(const float4*)&ffW[EE + lane * 4];
    #pragma unroll
    for (int rr = 0; rr < 8; ++rr) {
        int r = wave * 8 + rr;
        float4 v = *(const float4*)&a[r][lane * 4];
        float p1 = v.x * f1.x + v.y * f1.y + v.z * f1.z + v.w * f1.w;
        float p2 = v.x * f2.x + v.y * f2.y + v.z * f2.z + v.w * f2.w;
        #pragma unroll
        for (int off = 1; off <= 32; off <<= 1) {
            p1 += __shfl_xor(p1, off);
            p2 += __shfl_xor(p2, off);
        }
        if (lane == 0) {
            iefc[row0 + r] = p1;
            ieff[row0 + r] = p2;
        }
    }
}

__global__ __launch_bounds__(NTHR, 4) void k_main(
    const _Float16* __restrict__ ep, const float* __restrict__ yh,
    const _Float16* __restrict__ aW1h, const _Float16* __restrict__ WhhH,
    const float* __restrict__ bias_, const float* __restrict__ ab1,
    const float* __restrict__ aW2, const float* __restrict__ Wih,
    const float* __restrict__ fcW, const float* __restrict__ fcb,
    const float* __restrict__ ffW, const float* __restrict__ ffb,
    const float* __restrict__ iefc, const float* __restrict__ ieff,
    float* __restrict__ out) {
    __shared__ _Float16 s_ep[NB * TT * EE];      // 128 KB: block's ep slice
    __shared__ unsigned int s_hc16[NB][2][128];  // [b][0=h,1=c], f16 pairs
    __shared__ float s_qp[2][NB][EE];            // [kh][b][32*(f&7)+(f>>3)]
    __shared__ float s_sc[NB * TT];
    __shared__ float s_g[NB][4 * DD];            // h.Whh + bias (yt added later)
    __shared__ float s_wih[4 * DD];
    __shared__ float s_iefc[NB][TT];
    __shared__ float s_ieff[NB][TT];
    __shared__ float s_yh[NB][TT];

    const int tid = threadIdx.x;
    const int wave = tid >> 6, lane = tid & 63;
    const int b0 = blockIdx.x * NB;

    // ----- q mapping: thread = (qb, qkh, qf) -----
    const int qf = tid & 255, qkh = (tid >> 8) & 1, qb = tid >> 9;
    const float qinit = qkh ? 0.f : ab1[qf];
    const uint4* qW = (const uint4*)aW1h + ((size_t)(qkh * 32) * 256 + qf);
    const int qperm = 32 * (qf & 7) + (qf >> 3);

    // ----- gates mapping: thread = gate row tid -----
    const uint4* wP = (const uint4*)WhhH + tid;
    const float biasv = bias_[tid];

    // prefetch weight chunk 0 (iters 0..3) before any LDS dependency
    uint4 qw[4], gw[4];
    #pragma unroll
    for (int j = 0; j < 4; ++j) {
        qw[j] = qW[(size_t)j * 256];
        gw[j] = wP[(size_t)j * 1024];
    }

    // one-time staging
    {
        const uint4* src = (const uint4*)(ep + (size_t)b0 * TT * EE);
        uint4* dst = (uint4*)s_ep;
        #pragma unroll
        for (int i = 0; i < (NB * TT * EE) / 8 / NTHR; ++i)
            dst[tid + i * NTHR] = src[tid + i * NTHR];
    }
    for (int i = tid; i < 4 * DD; i += NTHR) s_wih[i] = Wih[i];
    for (int i = tid; i < NB * TT; i += NTHR) {
        int b = i >> 7, t = i & 127;
        s_iefc[b][t] = iefc[(b0 + b) * TT + t];
        s_ieff[b][t] = ieff[(b0 + b) * TT + t];
        s_yh[b][t]   = yh[(size_t)(b0 + b) * TT + t];
    }
    for (int i = tid; i < NB * 2 * 128; i += NTHR) (&s_hc16[0][0][0])[i] = 0u;

    // ----- scores mapping -----
    const int l5 = lane & 31;
    const int rsub = wave * 2 + (lane >> 5);     // [0,32)
    const int e0 = l5 * 8;
    float tw2[8]; float sw2 = 0.f;
    #pragma unroll
    for (int j = 0; j < 8; ++j) { float w = aW2[e0 + j]; tw2[j] = 2.f * w; sw2 += w; }

    // ----- softmax/update mapping: wave -> batch row -----
    const int bsm = (wave >> 2) & 1;             // waves 0-3:b0, 4-7:b1 (8-15 redundant)
    const float fcw256 = fcW[256], fcb0 = fcb[0], ffb0 = ffb[0];
    float c_reg = 0.f;                           // fp32 cell state (tid<512)
    float ofs_reg = 0.f;

    __syncthreads();

    for (int t = 0; t < TT; ++t) {
        // ---------- A: q = [h;c]@aW1 (+ab1)  AND  g = h@Whh.T + bias ----------
        // chunked register double-buffer: compute chunk cc while loading cc+1;
        // cc==7 prefetches chunk 0 for the NEXT step (same addresses).
        float qa = qinit;
        float g0 = biasv, g1 = biasv;
        #pragma unroll
        for (int cc = 0; cc < 8; ++cc) {
            uint4 qw2[4], gw2[4];
            const int nb = (cc + 1) & 7;
            #pragma unroll
            for (int j = 0; j < 4; ++j) {
                qw2[j] = qW[(size_t)(nb * 4 + j) * 256];
                gw2[j] = wP[(size_t)(nb * 4 + j) * 1024];
            }
            #pragma unroll
            for (int j = 0; j < 4; ++j) {
                const int i = cc * 4 + j;
                uint4 h0 = *(const uint4*)&s_hc16[0][0][i * 4];
                uint4 h1 = *(const uint4*)&s_hc16[1][0][i * 4];
                uint4 hq;
                if (qkh) hq = *(const uint4*)&s_hc16[qb][1][i * 4];
                else     hq = qb ? h1 : h0;
                qa = dot8u4(qw[j], hq, qa);
                g0 = dot8u4(gw[j], h0, g0);
                g1 = dot8u4(gw[j], h1, g1);
            }
            #pragma unroll
            for (int j = 0; j < 4; ++j) { qw[j] = qw2[j]; gw[j] = gw2[j]; }
        }
        s_qp[qkh][qb][qperm] = qa;
        s_g[0][tid] = g0;
        s_g[1][tid] = g1;
        __syncthreads();

        // ---------- B: scores s[b][t'] = sum_f w2[f]*tanh(qp0+qp1+ep) ----------
        #pragma unroll
        for (int b = 0; b < NB; ++b) {
            float qs[8];
            #pragma unroll
            for (int j = 0; j < 8; ++j)
                qs[j] = 2.f * (s_qp[0][b][l5 + 32 * j] + s_qp[1][b][l5 + 32 * j]);
            const _Float16* eph = s_ep + b * TT * EE + e0;
            #pragma unroll
            for (int sw = 0; sw < 4; ++sw) {
                int tt2 = sw * 32 + rsub;
                h8 xv = *(const h8*)(eph + tt2 * EE);
                float s = sw2;
                #pragma unroll
                for (int j = 0; j < 8; ++j) {
                    float e = __expf(__fmaf_rn((float)xv[j], 2.f, qs[j]));
                    s = __fmaf_rn(-tw2[j], __builtin_amdgcn_rcpf(e + 1.f), s);
                }
                #pragma unroll
                for (int off = 1; off <= 16; off <<= 1) s += __shfl_xor(s, off);
                if (l5 == 0) s_sc[b * TT + tt2] = s;
            }
        }
        __syncthreads();

        // ---------- C+D: all-wave shfl softmax + y_tilde + LSTM update ----------
        {
            float v0 = s_sc[bsm * TT + lane], v1 = s_sc[bsm * TT + 64 + lane];
            float m = fmaxf(v0, v1);
            #pragma unroll
            for (int off = 1; off <= 32; off <<= 1) m = fmaxf(m, __shfl_xor(m, off));
            float x0 = __expf(v0 - m), x1 = __expf(v1 - m);
            float ss = x0 + x1;
            #pragma unroll
            for (int off = 1; off <= 32; off <<= 1) ss += __shfl_xor(ss, off);
            float inv = __builtin_amdgcn_rcpf(ss);
            float a0 = x0 * inv, a1 = x1 * inv;
            float p = a0 * s_iefc[bsm][lane] + a1 * s_iefc[bsm][64 + lane];
            #pragma unroll
            for (int off = 1; off <= 32; off <<= 1) p += __shfl_xor(p, off);
            float yt = p + s_yh[bsm][t] * fcw256 + fcb0;
            if (t == TT - 1) {
                float pf = a0 * s_ieff[bsm][lane] + a1 * s_ieff[bsm][64 + lane];
                #pragma unroll
                for (int off = 1; off <= 32; off <<= 1) pf += __shfl_xor(pf, off);
                ofs_reg = pf;
            }
            if (tid < NB * DD) {
                int d = tid & 255;               // batch = bsm (waves 0-7)
                float gi = s_g[bsm][d]          + yt * s_wih[d];
                float gf = s_g[bsm][DD + d]     + yt * s_wih[DD + d];
                float gg = s_g[bsm][2 * DD + d] + yt * s_wih[2 * DD + d];
                float go = s_g[bsm][3 * DD + d] + yt * s_wih[3 * DD + d];
                float c2 = fsig(gf) * c_reg + fsig(gi) * ftanh(gg);
                c_reg = c2;
                float hn = fsig(go) * ftanh(c2);
                float hO = __shfl_xor(hn, 1);
                float cO = __shfl_xor(c2, 1);
                if (!(d & 1)) {
                    s_hc16[bsm][0][d >> 1] = pkh(hn, hO);
                    s_hc16[bsm][1][d >> 1] = pkh(c2, cO);
                }
            }
        }
        __syncthreads();
    }

    // ---------- final: out[b] = h.ffW[:256] + (attn_last . ieff) + ffb ----------
    if (wave == 0 || wave == 4) {
        int b = wave >> 2;
        unsigned int p0 = s_hc16[b][0][lane * 2];
        unsigned int p1 = s_hc16[b][0][lane * 2 + 1];
        h2 ha = __builtin_bit_cast(h2, p0), hb = __builtin_bit_cast(h2, p1);
        float4 w = *(const float4*)&ffW[lane * 4];
        float p = (float)ha[0] * w.x + (float)ha[1] * w.y
                + (float)hb[0] * w.z + (float)hb[1] * w.w;
        #pragma unroll
        for (int off = 1; off <= 32; off <<= 1) p += __shfl_xor(p, off);
        if (lane == 0) out[b0 + b] = p + ofs_reg + ffb0;
    }
}

extern "C" void kernel_launch(void* const* d_in, const int* in_sizes, int n_in,
                              void* d_out, int out_size, void* d_ws, size_t ws_size,
                              hipStream_t stream) {
    const float* ie  = (const float*)d_in[0];   // [B,T,E]
    const float* yh  = (const float*)d_in[1];   // [B,T,1]
    const float* aW1 = (const float*)d_in[2];   // [768,256]
    const float* ab1 = (const float*)d_in[3];   // [256]
    const float* aW2 = (const float*)d_in[4];   // [256,1]
    // d_in[5] = ab2: additive constant inside softmax -> invariant, unused
    const float* Wih = (const float*)d_in[6];   // [1024,1]
    const float* Whh = (const float*)d_in[7];   // [1024,256]
    const float* bih = (const float*)d_in[8];   // [1024]
    const float* bhh = (const float*)d_in[9];   // [1024]
    const float* fcW = (const float*)d_in[10];  // [1,257]
    const float* fcb = (const float*)d_in[11];  // [1]
    const float* ffW = (const float*)d_in[12];  // [1,512]
    const float* ffb = (const float*)d_in[13];  // [1]
    float* out = (float*)d_out;

    // workspace layout
    _Float16* ep   = (_Float16*)d_ws;                        // 16,777,216 f16 = 32 MiB
    _Float16* aW1h = ep + (size_t)BB * TT * EE;              // 131072 f16
    _Float16* WhhH = aW1h + 512 * EE;                        // 262144 f16
    float* bias = (float*)(WhhH + 262144);                   // 1024 f32
    float* iefc = bias + 1024;                               // 65536 f32
    float* ieff = iefc + BB * TT;                            // 65536 f32

    k_pack<<<1540, 256, 0, stream>>>(aW1, Whh, bih, bhh, aW1h, WhhH, bias);
    k_encproj<<<2048, 256, 0, stream>>>(ie, aW1, fcW, ffW, ep, iefc, ieff);
    k_main<<<BB / NB, NTHR, 0, stream>>>(ep, yh, aW1h, WhhH, bias, ab1, aW2,
                                         Wih, fcW, fcb, ffW, ffb, iefc, ieff, out);
}

// Round 9
// 13359.221 us; speedup vs baseline: 2.2346x; 2.2346x over previous
//
#include <hip/hip_runtime.h>

// DA-RNN decoder: B=512, T=128, E=256, D=256, OUT=1.
// R9: R6 lockstep base (one 1024-thread block/CU, NB=2 rows, ep in LDS),
// restructured so the L2 weight stream flows through ~the whole step:
//   A: q-GEMM 4-way K-split across all threads (aW1 read ONCE, was 2x)
//      + gates K-chunk 0..127
//   B: scores INTERLEAVED with gates K-chunk 128..255 (g0,g1 in regs across
//      the barrier; 4-iter weight chunks = 16 VGPRs, no spill)
//   C+D: redundant all-wave shfl softmax + LSTM update
// 3 barriers/step. h/c packed f16 in LDS; c fp32 in registers. No manual
// register rotation (R8 spilled: 40 GB scratch traffic).

#define BB 512
#define TT 128
#define EE 256
#define DD 256
#define NB 2
#define NTHR 1024

typedef _Float16 h2 __attribute__((ext_vector_type(2)));
typedef _Float16 h8 __attribute__((ext_vector_type(8)));

#if defined(__has_builtin)
#if __has_builtin(__builtin_amdgcn_fdot2)
#define HAS_FDOT2 1
#endif
#endif

#ifdef HAS_FDOT2
#define FDOT2(a, b, c) __builtin_amdgcn_fdot2(__builtin_bit_cast(h2, (a)), __builtin_bit_cast(h2, (b)), (c), false)
#else
static __device__ __forceinline__ float FDOT2(unsigned int a, unsigned int b, float c) {
    h2 x = __builtin_bit_cast(h2, a), y = __builtin_bit_cast(h2, b);
    return c + (float)x[0] * (float)y[0] + (float)x[1] * (float)y[1];
}
#endif

static __device__ __forceinline__ float dot8u4(uint4 w, uint4 h, float acc) {
    acc = FDOT2(w.x, h.x, acc);
    acc = FDOT2(w.y, h.y, acc);
    acc = FDOT2(w.z, h.z, acc);
    acc = FDOT2(w.w, h.w, acc);
    return acc;
}
static __device__ __forceinline__ unsigned int pkh(float a, float b) {
    union { _Float16 h; unsigned short s; } ua, ub;
    ua.h = (_Float16)a; ub.h = (_Float16)b;
    return (unsigned int)ua.s | ((unsigned int)ub.s << 16);
}
__device__ __forceinline__ float ftanh(float x) {
    return 1.f - 2.f * __builtin_amdgcn_rcpf(__expf(2.f * x) + 1.f);
}
__device__ __forceinline__ float fsig(float x) {
    return __builtin_amdgcn_rcpf(1.f + __expf(-x));
}

// Pack weights to f16 in the exact load order of k_main.
// aW1h[(g*256+f)*8+j] = aW1[g*8+j][f]      (g<64, k=g*8+j < 512)
// WhhH[(i*1024+jj)*8+m] = Whh[jj][i*8+m]   (i<32)
__global__ __launch_bounds__(256) void k_pack(const float* __restrict__ aW1,
                                              const float* __restrict__ Whh,
                                              const float* __restrict__ bih,
                                              const float* __restrict__ bhh,
                                              _Float16* __restrict__ aW1h,
                                              _Float16* __restrict__ WhhH,
                                              float* __restrict__ bias) {
    int bid = blockIdx.x, tid = threadIdx.x;
    if (bid < 512) {
        int o = bid * 256 + tid;                 // < 131072
        int g = o >> 11, f = (o >> 3) & 255, j = o & 7;
        aW1h[o] = (_Float16)aW1[(g * 8 + j) * EE + f];
    } else if (bid < 1536) {
        int o = (bid - 512) * 256 + tid;         // < 262144
        int i = o >> 13, jj = (o >> 3) & 1023, m = o & 7;
        WhhH[o] = (_Float16)Whh[jj * DD + i * 8 + m];
    } else {
        int j = (bid - 1536) * 256 + tid;        // < 1024
        bias[j] = bih[j] + bhh[j];
    }
}

// ep[n][f] = f16( sum_e ie[n][e]*aW1[512+e][f] )
// epilogue: iefc[n] = dot(ie[n], fcW[0:256]); ieff[n] = dot(ie[n], ffW[256:512])
__global__ __launch_bounds__(256) void k_encproj(const float* __restrict__ ie,
                                                 const float* __restrict__ aW1,
                                                 const float* __restrict__ fcW,
                                                 const float* __restrict__ ffW,
                                                 _Float16* __restrict__ ep,
                                                 float* __restrict__ iefc,
                                                 float* __restrict__ ieff) {
    __shared__ float a[32][EE];
    int row0 = blockIdx.x * 32;
    int tid = threadIdx.x;
    for (int r = 0; r < 32; ++r)
        a[r][tid] = ie[(size_t)(row0 + r) * EE + tid];
    __syncthreads();
    float acc[32];
    #pragma unroll
    for (int r = 0; r < 32; ++r) acc[r] = 0.f;
    const float* wenc = aW1 + 512 * EE;
    for (int e = 0; e < EE; e += 4) {
        float w0 = wenc[(e + 0) * EE + tid];
        float w1 = wenc[(e + 1) * EE + tid];
        float w2 = wenc[(e + 2) * EE + tid];
        float w3 = wenc[(e + 3) * EE + tid];
        #pragma unroll
        for (int r = 0; r < 32; ++r) {
            float4 av = *(const float4*)&a[r][e];
            acc[r] += av.x * w0 + av.y * w1 + av.z * w2 + av.w * w3;
        }
    }
    for (int r = 0; r < 32; ++r)
        ep[(size_t)(row0 + r) * EE + tid] = (_Float16)acc[r];

    int wave = tid >> 6, lane = tid & 63;
    float4 f1 = *(const float4*)&fcW[lane * 4];
    float4 f2 = *(const float4*)&ffW[EE + lane * 4];
    #pragma unroll
    for (int rr = 0; rr < 8; ++rr) {
        int r = wave * 8 + rr;
        float4 v = *(const float4*)&a[r][lane * 4];
        float p1 = v.x * f1.x + v.y * f1.y + v.z * f1.z + v.w * f1.w;
        float p2 = v.x * f2.x + v.y * f2.y + v.z * f2.z + v.w * f2.w;
        #pragma unroll
        for (int off = 1; off <= 32; off <<= 1) {
            p1 += __shfl_xor(p1, off);
            p2 += __shfl_xor(p2, off);
        }
        if (lane == 0) {
            iefc[row0 + r] = p1;
            ieff[row0 + r] = p2;
        }
    }
}

__global__ __launch_bounds__(NTHR) void k_main(
    const _Float16* __restrict__ ep, const float* __restrict__ yh,
    const _Float16* __restrict__ aW1h, const _Float16* __restrict__ WhhH,
    const float* __restrict__ bias_, const float* __restrict__ ab1,
    const float* __restrict__ aW2, const float* __restrict__ Wih,
    const float* __restrict__ fcW, const float* __restrict__ fcb,
    const float* __restrict__ ffW, const float* __restrict__ ffb,
    const float* __restrict__ iefc, const float* __restrict__ ieff,
    float* __restrict__ out) {
    __shared__ _Float16 s_ep[NB * TT * EE];      // 128 KB: block's ep slice
    __shared__ unsigned int s_hc16[NB][2][128];  // [b][0=h,1=c], f16 pairs
    __shared__ float s_qp[4][NB][EE];            // [kq][b][32*(f&7)+(f>>3)]
    __shared__ float s_sc[NB * TT];
    __shared__ float s_g[NB][4 * DD];            // h.Whh + bias (yt added later)
    __shared__ float s_wih[4 * DD];
    __shared__ float s_iefc[NB][TT];
    __shared__ float s_ieff[NB][TT];
    __shared__ float s_yh[NB][TT];

    const int tid = threadIdx.x;
    const int wave = tid >> 6, lane = tid & 63;
    const int b0 = blockIdx.x * NB;

    // one-time staging
    {
        const uint4* src = (const uint4*)(ep + (size_t)b0 * TT * EE);
        uint4* dst = (uint4*)s_ep;
        #pragma unroll
        for (int i = 0; i < (NB * TT * EE) / 8 / NTHR; ++i)
            dst[tid + i * NTHR] = src[tid + i * NTHR];
    }
    for (int i = tid; i < 4 * DD; i += NTHR) s_wih[i] = Wih[i];
    for (int i = tid; i < NB * TT; i += NTHR) {
        int b = i >> 7, t = i & 127;
        s_iefc[b][t] = iefc[(b0 + b) * TT + t];
        s_ieff[b][t] = ieff[(b0 + b) * TT + t];
        s_yh[b][t]   = yh[(size_t)(b0 + b) * TT + t];
    }
    for (int i = tid; i < NB * 2 * 128; i += NTHR) (&s_hc16[0][0][0])[i] = 0u;

    // ----- q mapping: thread = (kq, qf); kq = K-quarter, both batch rows -----
    const int qf = tid & 255, kq = tid >> 8;     // kq in [0,4)
    const float qinit = (kq == 0) ? ab1[qf] : 0.f;
    const uint4* qW = (const uint4*)aW1h + ((size_t)(kq * 16) * 256 + qf);
    const int qperm = 32 * (qf & 7) + (qf >> 3);
    const int qhc  = kq >> 1;                    // 0 = h-half, 1 = c-half
    const int qoff = (kq & 1) * 64;              // uint index base within row

    // ----- gates mapping: thread = gate row tid, both batch rows -----
    const uint4* wP = (const uint4*)WhhH + tid;
    const float biasv = bias_[tid];

    // ----- scores mapping -----
    const int l5 = lane & 31;
    const int rsub = wave * 2 + (lane >> 5);     // [0,32)
    const int e0 = l5 * 8;
    float tw2[8]; float sw2 = 0.f;
    #pragma unroll
    for (int j = 0; j < 8; ++j) { float w = aW2[e0 + j]; tw2[j] = 2.f * w; sw2 += w; }

    // ----- softmax/update mapping: wave -> batch row -----
    const int bsm = (wave >> 2) & 1;             // waves 0-3:b0, 4-7:b1 (8-15 redundant)
    const float fcw256 = fcW[256], fcb0 = fcb[0], ffb0 = ffb[0];
    float c_reg = 0.f;                           // fp32 cell state (tid<512)
    float ofs_reg = 0.f;

    __syncthreads();

    for (int t = 0; t < TT; ++t) {
        // ---------- A: q K-quarter (both rows) + gates K 0..127 ----------
        float qa0 = qinit, qa1 = qinit;
        float g0 = biasv, g1 = biasv;
        #pragma unroll
        for (int i = 0; i < 16; ++i) {
            uint4 qwv = qW[(size_t)i * 256];
            uint4 gwv = wP[(size_t)i * 1024];
            uint4 hq0 = *(const uint4*)&s_hc16[0][qhc][qoff + i * 4];
            uint4 hq1 = *(const uint4*)&s_hc16[1][qhc][qoff + i * 4];
            uint4 h0  = *(const uint4*)&s_hc16[0][0][i * 4];
            uint4 h1  = *(const uint4*)&s_hc16[1][0][i * 4];
            qa0 = dot8u4(qwv, hq0, qa0);
            qa1 = dot8u4(qwv, hq1, qa1);
            g0  = dot8u4(gwv, h0, g0);
            g1  = dot8u4(gwv, h1, g1);
        }
        s_qp[kq][0][qperm] = qa0;
        s_qp[kq][1][qperm] = qa1;
        __syncthreads();

        // ---------- B: scores interleaved with gates K 128..255 ----------
        float qs0[8], qs1[8];
        #pragma unroll
        for (int j = 0; j < 8; ++j) {
            int ix = l5 + 32 * j;
            qs0[j] = 2.f * (s_qp[0][0][ix] + s_qp[1][0][ix] + s_qp[2][0][ix] + s_qp[3][0][ix]);
            qs1[j] = 2.f * (s_qp[0][1][ix] + s_qp[1][1][ix] + s_qp[2][1][ix] + s_qp[3][1][ix]);
        }
        #pragma unroll
        for (int c = 0; c < 4; ++c) {
            uint4 gwv[4];
            #pragma unroll
            for (int j = 0; j < 4; ++j)
                gwv[j] = wP[(size_t)(16 + c * 4 + j) * 1024];
            // two score groups while the 4 weight loads are in flight
            #pragma unroll
            for (int p = 2 * c; p < 2 * c + 2; ++p) {
                const int b = p >> 2, sw = p & 3;
                int tt2 = sw * 32 + rsub;
                h8 xv = *(const h8*)(s_ep + b * TT * EE + tt2 * EE + e0);
                float s = sw2;
                #pragma unroll
                for (int j = 0; j < 8; ++j) {
                    float e = __expf(__fmaf_rn((float)xv[j], 2.f, b ? qs1[j] : qs0[j]));
                    s = __fmaf_rn(-tw2[j], __builtin_amdgcn_rcpf(e + 1.f), s);
                }
                #pragma unroll
                for (int off = 1; off <= 16; off <<= 1) s += __shfl_xor(s, off);
                if (l5 == 0) s_sc[b * TT + tt2] = s;
            }
            #pragma unroll
            for (int j = 0; j < 4; ++j) {
                const int i = 16 + c * 4 + j;
                uint4 h0 = *(const uint4*)&s_hc16[0][0][i * 4];
                uint4 h1 = *(const uint4*)&s_hc16[1][0][i * 4];
                g0 = dot8u4(gwv[j], h0, g0);
                g1 = dot8u4(gwv[j], h1, g1);
            }
        }
        s_g[0][tid] = g0;
        s_g[1][tid] = g1;
        __syncthreads();

        // ---------- C+D: all-wave shfl softmax + y_tilde + LSTM update ----------
        {
            float v0 = s_sc[bsm * TT + lane], v1 = s_sc[bsm * TT + 64 + lane];
            float m = fmaxf(v0, v1);
            #pragma unroll
            for (int off = 1; off <= 32; off <<= 1) m = fmaxf(m, __shfl_xor(m, off));
            float x0 = __expf(v0 - m), x1 = __expf(v1 - m);
            float ss = x0 + x1;
            #pragma unroll
            for (int off = 1; off <= 32; off <<= 1) ss += __shfl_xor(ss, off);
            float inv = __builtin_amdgcn_rcpf(ss);
            float a0 = x0 * inv, a1 = x1 * inv;
            float p = a0 * s_iefc[bsm][lane] + a1 * s_iefc[bsm][64 + lane];
            #pragma unroll
            for (int off = 1; off <= 32; off <<= 1) p += __shfl_xor(p, off);
            float yt = p + s_yh[bsm][t] * fcw256 + fcb0;
            if (t == TT - 1) {
                float pf = a0 * s_ieff[bsm][lane] + a1 * s_ieff[bsm][64 + lane];
                #pragma unroll
                for (int off = 1; off <= 32; off <<= 1) pf += __shfl_xor(pf, off);
                ofs_reg = pf;
            }
            if (tid < NB * DD) {
                int d = tid & 255;               // batch row = bsm (waves 0-7)
                float gi = s_g[bsm][d]          + yt * s_wih[d];
                float gf = s_g[bsm][DD + d]     + yt * s_wih[DD + d];
                float gg = s_g[bsm][2 * DD + d] + yt * s_wih[2 * DD + d];
                float go = s_g[bsm][3 * DD + d] + yt * s_wih[3 * DD + d];
                float c2 = fsig(gf) * c_reg + fsig(gi) * ftanh(gg);
                c_reg = c2;
                float hn = fsig(go) * ftanh(c2);
                float hO = __shfl_xor(hn, 1);
                float cO = __shfl_xor(c2, 1);
                if (!(d & 1)) {
                    s_hc16[bsm][0][d >> 1] = pkh(hn, hO);
                    s_hc16[bsm][1][d >> 1] = pkh(c2, cO);
                }
            }
        }
        __syncthreads();
    }

    // ---------- final: out[b] = h.ffW[:256] + (attn_last . ieff) + ffb ----------
    if (wave == 0 || wave == 4) {
        int b = wave >> 2;
        unsigned int p0 = s_hc16[b][0][lane * 2];
        unsigned int p1 = s_hc16[b][0][lane * 2 + 1];
        h2 ha = __builtin_bit_cast(h2, p0), hb = __builtin_bit_cast(h2, p1);
        float4 w = *(const float4*)&ffW[lane * 4];
        float p = (float)ha[0] * w.x + (float)ha[1] * w.y
                + (float)hb[0] * w.z + (float)hb[1] * w.w;
        #pragma unroll
        for (int off = 1; off <= 32; off <<= 1) p += __shfl_xor(p, off);
        if (lane == 0) out[b0 + b] = p + ofs_reg + ffb0;
    }
}

extern "C" void kernel_launch(void* const* d_in, const int* in_sizes, int n_in,
                              void* d_out, int out_size, void* d_ws, size_t ws_size,
                              hipStream_t stream) {
    const float* ie  = (const float*)d_in[0];   // [B,T,E]
    const float* yh  = (const float*)d_in[1];   // [B,T,1]
    const float* aW1 = (const float*)d_in[2];   // [768,256]
    const float* ab1 = (const float*)d_in[3];   // [256]
    const float* aW2 = (const float*)d_in[4];   // [256,1]
    // d_in[5] = ab2: additive constant inside softmax -> invariant, unused
    const float* Wih = (const float*)d_in[6];   // [1024,1]
    const float* Whh = (const float*)d_in[7];   // [1024,256]
    const float* bih = (const float*)d_in[8];   // [1024]
    const float* bhh = (const float*)d_in[9];   // [1024]
    const float* fcW = (const float*)d_in[10];  // [1,257]
    const float* fcb = (const float*)d_in[11];  // [1]
    const float* ffW = (const float*)d_in[12];  // [1,512]
    const float* ffb = (const float*)d_in[13];  // [1]
    float* out = (float*)d_out;

    // workspace layout
    _Float16* ep   = (_Float16*)d_ws;                        // 16,777,216 f16 = 32 MiB
    _Float16* aW1h = ep + (size_t)BB * TT * EE;              // 131072 f16
    _Float16* WhhH = aW1h + 512 * EE;                        // 262144 f16
    float* bias = (float*)(WhhH + 262144);                   // 1024 f32
    float* iefc = bias + 1024;                               // 65536 f32
    float* ieff = iefc + BB * TT;                            // 65536 f32

    k_pack<<<1540, 256, 0, stream>>>(aW1, Whh, bih, bhh, aW1h, WhhH, bias);
    k_encproj<<<2048, 256, 0, stream>>>(ie, aW1, fcW, ffW, ep, iefc, ieff);
    k_main<<<BB / NB, NTHR, 0, stream>>>(ep, yh, aW1h, WhhH, bias, ab1, aW2,
                                         Wih, fcW, fcb, ffW, ffb, iefc, ieff, out);
}

// Round 10
// 3688.542 us; speedup vs baseline: 8.0934x; 3.6218x over previous
//
#include <hip/hip_runtime.h>

// DA-RNN decoder: B=512, T=128, E=256, D=256, OUT=1.
// R10: R6 lockstep base (one 1024-thread block/CU, NB=2 rows, ep in LDS)
// with three safe deltas (NO register arrays -- R8/R9 spilled via rule #20):
//  1. phase-A weight loads pipelined 1-deep via individually NAMED uint4 vars
//     (qw_a/ga_a/gb_a vs qw_b/ga_b/gb_b), next-step i=0 prefetched at tail.
//  2. q-GEMM 4-way K-split (aW1 read once, no duplicate).
//  3. phases C+D merged: redundant all-wave shfl softmax + LSTM update.
// 3 barriers/step. h/c packed f16 in LDS; c fp32 in registers.

#define BB 512
#define TT 128
#define EE 256
#define DD 256
#define NB 2
#define NTHR 1024

typedef _Float16 h2 __attribute__((ext_vector_type(2)));
typedef _Float16 h8 __attribute__((ext_vector_type(8)));

#if defined(__has_builtin)
#if __has_builtin(__builtin_amdgcn_fdot2)
#define HAS_FDOT2 1
#endif
#endif

#ifdef HAS_FDOT2
#define FDOT2(a, b, c) __builtin_amdgcn_fdot2(__builtin_bit_cast(h2, (a)), __builtin_bit_cast(h2, (b)), (c), false)
#else
static __device__ __forceinline__ float FDOT2(unsigned int a, unsigned int b, float c) {
    h2 x = __builtin_bit_cast(h2, a), y = __builtin_bit_cast(h2, b);
    return c + (float)x[0] * (float)y[0] + (float)x[1] * (float)y[1];
}
#endif

static __device__ __forceinline__ float dot8u4(uint4 w, uint4 h, float acc) {
    acc = FDOT2(w.x, h.x, acc);
    acc = FDOT2(w.y, h.y, acc);
    acc = FDOT2(w.z, h.z, acc);
    acc = FDOT2(w.w, h.w, acc);
    return acc;
}
static __device__ __forceinline__ unsigned int pkh(float a, float b) {
    union { _Float16 h; unsigned short s; } ua, ub;
    ua.h = (_Float16)a; ub.h = (_Float16)b;
    return (unsigned int)ua.s | ((unsigned int)ub.s << 16);
}
__device__ __forceinline__ float ftanh(float x) {
    return 1.f - 2.f * __builtin_amdgcn_rcpf(__expf(2.f * x) + 1.f);
}
__device__ __forceinline__ float fsig(float x) {
    return __builtin_amdgcn_rcpf(1.f + __expf(-x));
}

// Pack weights to f16 in the exact load order of k_main.
// aW1h[(g*256+f)*8+j] = aW1[g*8+j][f]      (g<64, k=g*8+j < 512)
// WhhH[(i*1024+jj)*8+m] = Whh[jj][i*8+m]   (i<32)
__global__ __launch_bounds__(256) void k_pack(const float* __restrict__ aW1,
                                              const float* __restrict__ Whh,
                                              const float* __restrict__ bih,
                                              const float* __restrict__ bhh,
                                              _Float16* __restrict__ aW1h,
                                              _Float16* __restrict__ WhhH,
                                              float* __restrict__ bias) {
    int bid = blockIdx.x, tid = threadIdx.x;
    if (bid < 512) {
        int o = bid * 256 + tid;                 // < 131072
        int g = o >> 11, f = (o >> 3) & 255, j = o & 7;
        aW1h[o] = (_Float16)aW1[(g * 8 + j) * EE + f];
    } else if (bid < 1536) {
        int o = (bid - 512) * 256 + tid;         // < 262144
        int i = o >> 13, jj = (o >> 3) & 1023, m = o & 7;
        WhhH[o] = (_Float16)Whh[jj * DD + i * 8 + m];
    } else {
        int j = (bid - 1536) * 256 + tid;        // < 1024
        bias[j] = bih[j] + bhh[j];
    }
}

// ep[n][f] = f16( sum_e ie[n][e]*aW1[512+e][f] )
// epilogue: iefc[n] = dot(ie[n], fcW[0:256]); ieff[n] = dot(ie[n], ffW[256:512])
__global__ __launch_bounds__(256) void k_encproj(const float* __restrict__ ie,
                                                 const float* __restrict__ aW1,
                                                 const float* __restrict__ fcW,
                                                 const float* __restrict__ ffW,
                                                 _Float16* __restrict__ ep,
                                                 float* __restrict__ iefc,
                                                 float* __restrict__ ieff) {
    __shared__ float a[32][EE];
    int row0 = blockIdx.x * 32;
    int tid = threadIdx.x;
    for (int r = 0; r < 32; ++r)
        a[r][tid] = ie[(size_t)(row0 + r) * EE + tid];
    __syncthreads();
    float acc[32];
    #pragma unroll
    for (int r = 0; r < 32; ++r) acc[r] = 0.f;
    const float* wenc = aW1 + 512 * EE;
    for (int e = 0; e < EE; e += 4) {
        float w0 = wenc[(e + 0) * EE + tid];
        float w1 = wenc[(e + 1) * EE + tid];
        float w2 = wenc[(e + 2) * EE + tid];
        float w3 = wenc[(e + 3) * EE + tid];
        #pragma unroll
        for (int r = 0; r < 32; ++r) {
            float4 av = *(const float4*)&a[r][e];
            acc[r] += av.x * w0 + av.y * w1 + av.z * w2 + av.w * w3;
        }
    }
    for (int r = 0; r < 32; ++r)
        ep[(size_t)(row0 + r) * EE + tid] = (_Float16)acc[r];

    int wave = tid >> 6, lane = tid & 63;
    float4 f1 = *(const float4*)&fcW[lane * 4];
    float4 f2 = *(const float4*)&ffW[EE + lane * 4];
    #pragma unroll
    for (int rr = 0; rr < 8; ++rr) {
        int r = wave * 8 + rr;
        float4 v = *(const float4*)&a[r][lane * 4];
        float p1 = v.x * f1.x + v.y * f1.y + v.z * f1.z + v.w * f1.w;
        float p2 = v.x * f2.x + v.y * f2.y + v.z * f2.z + v.w * f2.w;
        #pragma unroll
        for (int off = 1; off <= 32; off <<= 1) {
            p1 += __shfl_xor(p1, off);
            p2 += __shfl_xor(p2, off);
        }
        if (lane == 0) {
            iefc[row0 + r] = p1;
            ieff[row0 + r] = p2;
        }
    }
}

__global__ __launch_bounds__(NTHR, 4) void k_main(
    const _Float16* __restrict__ ep, const float* __restrict__ yh,
    const _Float16* __restrict__ aW1h, const _Float16* __restrict__ WhhH,
    const float* __restrict__ bias_, const float* __restrict__ ab1,
    const float* __restrict__ aW2, const float* __restrict__ Wih,
    const float* __restrict__ fcW, const float* __restrict__ fcb,
    const float* __restrict__ ffW, const float* __restrict__ ffb,
    const float* __restrict__ iefc, const float* __restrict__ ieff,
    float* __restrict__ out) {
    __shared__ _Float16 s_ep[NB * TT * EE];      // 128 KB: block's ep slice
    __shared__ unsigned int s_hc16[NB][2][128];  // [b][0=h,1=c], f16 pairs
    __shared__ float s_qp[4][NB][EE];            // [kq][b][32*(f&7)+(f>>3)]
    __shared__ float s_sc[NB * TT];
    __shared__ float s_g[NB][4 * DD];            // h.Whh + bias (yt added later)
    __shared__ float s_wih[4 * DD];
    __shared__ float s_iefc[NB][TT];
    __shared__ float s_ieff[NB][TT];
    __shared__ float s_yh[NB][TT];

    const int tid = threadIdx.x;
    const int wave = tid >> 6, lane = tid & 63;
    const int b0 = blockIdx.x * NB;

    // one-time staging
    {
        const uint4* src = (const uint4*)(ep + (size_t)b0 * TT * EE);
        uint4* dst = (uint4*)s_ep;
        #pragma unroll
        for (int i = 0; i < (NB * TT * EE) / 8 / NTHR; ++i)
            dst[tid + i * NTHR] = src[tid + i * NTHR];
    }
    for (int i = tid; i < 4 * DD; i += NTHR) s_wih[i] = Wih[i];
    for (int i = tid; i < NB * TT; i += NTHR) {
        int b = i >> 7, t = i & 127;
        s_iefc[b][t] = iefc[(b0 + b) * TT + t];
        s_ieff[b][t] = ieff[(b0 + b) * TT + t];
        s_yh[b][t]   = yh[(size_t)(b0 + b) * TT + t];
    }
    for (int i = tid; i < NB * 2 * 128; i += NTHR) (&s_hc16[0][0][0])[i] = 0u;

    // ----- q mapping: thread = (kq, qf); kq = K-quarter, both batch rows -----
    const int qf = tid & 255, kq = tid >> 8;     // kq in [0,4)
    const float qinit = (kq == 0) ? ab1[qf] : 0.f;
    const uint4* qW = (const uint4*)aW1h + ((size_t)(kq * 16) * 256 + qf);
    const int qperm = 32 * (qf & 7) + (qf >> 3);
    const int qhc  = kq >> 1;                    // 0 = h-half, 1 = c-half
    const int qoff = (kq & 1) * 64;              // uint index base within row

    // ----- gates mapping: thread = gate row tid (both batch rows) -----
    const uint4* wP = (const uint4*)WhhH + tid;
    const float biasv = bias_[tid];

    // ----- scores mapping -----
    const int l5 = lane & 31;
    const int rsub = wave * 2 + (lane >> 5);     // [0,32)
    const int e0 = l5 * 8;
    float tw2[8]; float sw2 = 0.f;
    #pragma unroll
    for (int j = 0; j < 8; ++j) { float w = aW2[e0 + j]; tw2[j] = 2.f * w; sw2 += w; }

    // ----- softmax/update mapping: wave -> batch row -----
    const int bsm = (wave >> 2) & 1;             // waves 0-3:b0, 4-7:b1 (8-15 redundant)
    const float fcw256 = fcW[256], fcb0 = fcb[0], ffb0 = ffb[0];
    float c_reg = 0.f;                           // fp32 cell state (tid<512)
    float ofs_reg = 0.f;

    // steady 1-deep weight prefetch (named vars only; addresses step-invariant)
    uint4 qw_a = qW[0];
    uint4 ga_a = wP[0];
    uint4 gb_a = wP[(size_t)16 * 1024];

    __syncthreads();

    for (int t = 0; t < TT; ++t) {
        // ---------- A: q K-quarter (both rows) + gates, 1-deep pipelined ----------
        float qa0 = qinit, qa1 = qinit;
        float g0 = biasv, g1 = biasv;
        #pragma unroll
        for (int i = 0; i < 16; i += 2) {
            // issue loads for iter i+1
            uint4 qw_b = qW[(size_t)(i + 1) * 256];
            uint4 ga_b = wP[(size_t)(i + 1) * 1024];
            uint4 gb_b = wP[(size_t)(i + 17) * 1024];
            // compute iter i from _a
            {
                uint4 hq0 = *(const uint4*)&s_hc16[0][qhc][qoff + i * 4];
                uint4 hq1 = *(const uint4*)&s_hc16[1][qhc][qoff + i * 4];
                uint4 h0  = *(const uint4*)&s_hc16[0][0][i * 4];
                uint4 h1  = *(const uint4*)&s_hc16[1][0][i * 4];
                uint4 h0b = *(const uint4*)&s_hc16[0][0][(i + 16) * 4];
                uint4 h1b = *(const uint4*)&s_hc16[1][0][(i + 16) * 4];
                qa0 = dot8u4(qw_a, hq0, qa0);
                qa1 = dot8u4(qw_a, hq1, qa1);
                g0 = dot8u4(ga_a, h0, g0);
                g1 = dot8u4(ga_a, h1, g1);
                g0 = dot8u4(gb_a, h0b, g0);
                g1 = dot8u4(gb_a, h1b, g1);
            }
            // issue loads for iter i+2 (wraps to 0 at i=14 -> next step's prologue)
            {
                const int n = (i + 2) & 15;
                qw_a = qW[(size_t)n * 256];
                ga_a = wP[(size_t)n * 1024];
                gb_a = wP[(size_t)(n + 16) * 1024];
            }
            // compute iter i+1 from _b
            {
                const int i1 = i + 1;
                uint4 hq0 = *(const uint4*)&s_hc16[0][qhc][qoff + i1 * 4];
                uint4 hq1 = *(const uint4*)&s_hc16[1][qhc][qoff + i1 * 4];
                uint4 h0  = *(const uint4*)&s_hc16[0][0][i1 * 4];
                uint4 h1  = *(const uint4*)&s_hc16[1][0][i1 * 4];
                uint4 h0b = *(const uint4*)&s_hc16[0][0][(i1 + 16) * 4];
                uint4 h1b = *(const uint4*)&s_hc16[1][0][(i1 + 16) * 4];
                qa0 = dot8u4(qw_b, hq0, qa0);
                qa1 = dot8u4(qw_b, hq1, qa1);
                g0 = dot8u4(ga_b, h0, g0);
                g1 = dot8u4(ga_b, h1, g1);
                g0 = dot8u4(gb_b, h0b, g0);
                g1 = dot8u4(gb_b, h1b, g1);
            }
        }
        s_qp[kq][0][qperm] = qa0;
        s_qp[kq][1][qperm] = qa1;
        s_g[0][tid] = g0;
        s_g[1][tid] = g1;
        __syncthreads();

        // ---------- B: scores s[b][t'] = sum_f w2[f]*tanh(q+ep+ab1) ----------
        #pragma unroll
        for (int b = 0; b < NB; ++b) {
            float qs[8];
            #pragma unroll
            for (int j = 0; j < 8; ++j) {
                int ix = l5 + 32 * j;
                qs[j] = 2.f * (s_qp[0][b][ix] + s_qp[1][b][ix]
                             + s_qp[2][b][ix] + s_qp[3][b][ix]);
            }
            const _Float16* eph = s_ep + b * TT * EE + e0;
            #pragma unroll
            for (int sw = 0; sw < 4; ++sw) {
                int tt2 = sw * 32 + rsub;
                h8 xv = *(const h8*)(eph + tt2 * EE);
                float s = sw2;
                #pragma unroll
                for (int j = 0; j < 8; ++j) {
                    float e = __expf(__fmaf_rn((float)xv[j], 2.f, qs[j]));
                    s = __fmaf_rn(-tw2[j], __builtin_amdgcn_rcpf(e + 1.f), s);
                }
                #pragma unroll
                for (int off = 1; off <= 16; off <<= 1) s += __shfl_xor(s, off);
                if (l5 == 0) s_sc[b * TT + tt2] = s;
            }
        }
        __syncthreads();

        // ---------- C+D: all-wave shfl softmax + y_tilde + LSTM update ----------
        {
            float v0 = s_sc[bsm * TT + lane], v1 = s_sc[bsm * TT + 64 + lane];
            float m = fmaxf(v0, v1);
            #pragma unroll
            for (int off = 1; off <= 32; off <<= 1) m = fmaxf(m, __shfl_xor(m, off));
            float x0 = __expf(v0 - m), x1 = __expf(v1 - m);
            float ss = x0 + x1;
            #pragma unroll
            for (int off = 1; off <= 32; off <<= 1) ss += __shfl_xor(ss, off);
            float inv = __builtin_amdgcn_rcpf(ss);
            float a0 = x0 * inv, a1 = x1 * inv;
            float p = a0 * s_iefc[bsm][lane] + a1 * s_iefc[bsm][64 + lane];
            #pragma unroll
            for (int off = 1; off <= 32; off <<= 1) p += __shfl_xor(p, off);
            float yt = p + s_yh[bsm][t] * fcw256 + fcb0;
            if (t == TT - 1) {
                float pf = a0 * s_ieff[bsm][lane] + a1 * s_ieff[bsm][64 + lane];
                #pragma unroll
                for (int off = 1; off <= 32; off <<= 1) pf += __shfl_xor(pf, off);
                ofs_reg = pf;
            }
            if (tid < NB * DD) {
                int d = tid & 255;               // batch row = bsm (waves 0-7)
                float gi = s_g[bsm][d]          + yt * s_wih[d];
                float gf = s_g[bsm][DD + d]     + yt * s_wih[DD + d];
                float gg = s_g[bsm][2 * DD + d] + yt * s_wih[2 * DD + d];
                float go = s_g[bsm][3 * DD + d] + yt * s_wih[3 * DD + d];
                float c2 = fsig(gf) * c_reg + fsig(gi) * ftanh(gg);
                c_reg = c2;
                float hn = fsig(go) * ftanh(c2);
                float hO = __shfl_xor(hn, 1);
                float cO = __shfl_xor(c2, 1);
                if (!(d & 1)) {
                    s_hc16[bsm][0][d >> 1] = pkh(hn, hO);
                    s_hc16[bsm][1][d >> 1] = pkh(c2, cO);
                }
            }
        }
        __syncthreads();
    }

    // ---------- final: out[b] = h.ffW[:256] + (attn_last . ieff) + ffb ----------
    if (wave == 0 || wave == 4) {
        int b = wave >> 2;
        unsigned int p0 = s_hc16[b][0][lane * 2];
        unsigned int p1 = s_hc16[b][0][lane * 2 + 1];
        h2 ha = __builtin_bit_cast(h2, p0), hb = __builtin_bit_cast(h2, p1);
        float4 w = *(const float4*)&ffW[lane * 4];
        float p = (float)ha[0] * w.x + (float)ha[1] * w.y
                + (float)hb[0] * w.z + (float)hb[1] * w.w;
        #pragma unroll
        for (int off = 1; off <= 32; off <<= 1) p += __shfl_xor(p, off);
        if (lane == 0) out[b0 + b] = p + ofs_reg + ffb0;
    }
}

extern "C" void kernel_launch(void* const* d_in, const int* in_sizes, int n_in,
                              void* d_out, int out_size, void* d_ws, size_t ws_size,
                              hipStream_t stream) {
    const float* ie  = (const float*)d_in[0];   // [B,T,E]
    const float* yh  = (const float*)d_in[1];   // [B,T,1]
    const float* aW1 = (const float*)d_in[2];   // [768,256]
    const float* ab1 = (const float*)d_in[3];   // [256]
    const float* aW2 = (const float*)d_in[4];   // [256,1]
    // d_in[5] = ab2: additive constant inside softmax -> invariant, unused
    const float* Wih = (const float*)d_in[6];   // [1024,1]
    const float* Whh = (const float*)d_in[7];   // [1024,256]
    const float* bih = (const float*)d_in[8];   // [1024]
    const float* bhh = (const float*)d_in[9];   // [1024]
    const float* fcW = (const float*)d_in[10];  // [1,257]
    const float* fcb = (const float*)d_in[11];  // [1]
    const float* ffW = (const float*)d_in[12];  // [1,512]
    const float* ffb = (const float*)d_in[13];  // [1]
    float* out = (float*)d_out;

    // workspace layout
    _Float16* ep   = (_Float16*)d_ws;                        // 16,777,216 f16 = 32 MiB
    _Float16* aW1h = ep + (size_t)BB * TT * EE;              // 131072 f16
    _Float16* WhhH = aW1h + 512 * EE;                        // 262144 f16
    float* bias = (float*)(WhhH + 262144);                   // 1024 f32
    float* iefc = bias + 1024;                               // 65536 f32
    float* ieff = iefc + BB * TT;                            // 65536 f32

    k_pack<<<1540, 256, 0, stream>>>(aW1, Whh, bih, bhh, aW1h, WhhH, bias);
    k_encproj<<<2048, 256, 0, stream>>>(ie, aW1, fcW, ffW, ep, iefc, ieff);
    k_main<<<BB / NB, NTHR, 0, stream>>>(ep, yh, aW1h, WhhH, bias, ab1, aW2,
                                         Wih, fcW, fcb, ffW, ffb, iefc, ieff, out);
}

// Round 11
// 3597.515 us; speedup vs baseline: 8.2982x; 1.0253x over previous
//
#include <hip/hip_runtime.h>

// DA-RNN decoder: B=512, T=128, E=256, D=256, OUT=1.
// R11 = R6 base (one 1024-thread block/CU, lockstep 3 phases, ep in LDS,
// simple non-rotated loads -- R8/R9/R10 proved ANY manual load rotation
// spills) + two weight-BYTE cuts (the binding resource is the per-CU L2
// weight stream):
//  1. q-GEMM 4-way K-split: aW1 streamed once (was 2x).
//  2. 12 uint4 of Whh (k in [160,256)) parked in write-once named registers
//     wr0..wr11 before the t-loop (VGPR budget 128, R6 used 52).
// Stream: 1 MB -> 576 KB per step per CU. Merged C+D (all-wave softmax).

#define BB 512
#define TT 128
#define EE 256
#define DD 256
#define NB 2
#define NTHR 1024

typedef _Float16 h2 __attribute__((ext_vector_type(2)));
typedef _Float16 h8 __attribute__((ext_vector_type(8)));

#if defined(__has_builtin)
#if __has_builtin(__builtin_amdgcn_fdot2)
#define HAS_FDOT2 1
#endif
#endif

#ifdef HAS_FDOT2
#define FDOT2(a, b, c) __builtin_amdgcn_fdot2(__builtin_bit_cast(h2, (a)), __builtin_bit_cast(h2, (b)), (c), false)
#else
static __device__ __forceinline__ float FDOT2(unsigned int a, unsigned int b, float c) {
    h2 x = __builtin_bit_cast(h2, a), y = __builtin_bit_cast(h2, b);
    return c + (float)x[0] * (float)y[0] + (float)x[1] * (float)y[1];
}
#endif

static __device__ __forceinline__ float dot8u4(uint4 w, uint4 h, float acc) {
    acc = FDOT2(w.x, h.x, acc);
    acc = FDOT2(w.y, h.y, acc);
    acc = FDOT2(w.z, h.z, acc);
    acc = FDOT2(w.w, h.w, acc);
    return acc;
}
static __device__ __forceinline__ unsigned int pkh(float a, float b) {
    union { _Float16 h; unsigned short s; } ua, ub;
    ua.h = (_Float16)a; ub.h = (_Float16)b;
    return (unsigned int)ua.s | ((unsigned int)ub.s << 16);
}
__device__ __forceinline__ float ftanh(float x) {
    return 1.f - 2.f * __builtin_amdgcn_rcpf(__expf(2.f * x) + 1.f);
}
__device__ __forceinline__ float fsig(float x) {
    return __builtin_amdgcn_rcpf(1.f + __expf(-x));
}

// Pack weights to f16 in the exact load order of k_main.
// aW1h[(g*256+f)*8+j] = aW1[g*8+j][f]      (g<64, k=g*8+j < 512)
// WhhH[(i*1024+jj)*8+m] = Whh[jj][i*8+m]   (i<32)
__global__ __launch_bounds__(256) void k_pack(const float* __restrict__ aW1,
                                              const float* __restrict__ Whh,
                                              const float* __restrict__ bih,
                                              const float* __restrict__ bhh,
                                              _Float16* __restrict__ aW1h,
                                              _Float16* __restrict__ WhhH,
                                              float* __restrict__ bias) {
    int bid = blockIdx.x, tid = threadIdx.x;
    if (bid < 512) {
        int o = bid * 256 + tid;                 // < 131072
        int g = o >> 11, f = (o >> 3) & 255, j = o & 7;
        aW1h[o] = (_Float16)aW1[(g * 8 + j) * EE + f];
    } else if (bid < 1536) {
        int o = (bid - 512) * 256 + tid;         // < 262144
        int i = o >> 13, jj = (o >> 3) & 1023, m = o & 7;
        WhhH[o] = (_Float16)Whh[jj * DD + i * 8 + m];
    } else {
        int j = (bid - 1536) * 256 + tid;        // < 1024
        bias[j] = bih[j] + bhh[j];
    }
}

// ep[n][f] = f16( sum_e ie[n][e]*aW1[512+e][f] )
// epilogue: iefc[n] = dot(ie[n], fcW[0:256]); ieff[n] = dot(ie[n], ffW[256:512])
__global__ __launch_bounds__(256) void k_encproj(const float* __restrict__ ie,
                                                 const float* __restrict__ aW1,
                                                 const float* __restrict__ fcW,
                                                 const float* __restrict__ ffW,
                                                 _Float16* __restrict__ ep,
                                                 float* __restrict__ iefc,
                                                 float* __restrict__ ieff) {
    __shared__ float a[32][EE];
    int row0 = blockIdx.x * 32;
    int tid = threadIdx.x;
    for (int r = 0; r < 32; ++r)
        a[r][tid] = ie[(size_t)(row0 + r) * EE + tid];
    __syncthreads();
    float acc[32];
    #pragma unroll
    for (int r = 0; r < 32; ++r) acc[r] = 0.f;
    const float* wenc = aW1 + 512 * EE;
    for (int e = 0; e < EE; e += 4) {
        float w0 = wenc[(e + 0) * EE + tid];
        float w1 = wenc[(e + 1) * EE + tid];
        float w2 = wenc[(e + 2) * EE + tid];
        float w3 = wenc[(e + 3) * EE + tid];
        #pragma unroll
        for (int r = 0; r < 32; ++r) {
            float4 av = *(const float4*)&a[r][e];
            acc[r] += av.x * w0 + av.y * w1 + av.z * w2 + av.w * w3;
        }
    }
    for (int r = 0; r < 32; ++r)
        ep[(size_t)(row0 + r) * EE + tid] = (_Float16)acc[r];

    int wave = tid >> 6, lane = tid & 63;
    float4 f1 = *(const float4*)&fcW[lane * 4];
    float4 f2 = *(const float4*)&ffW[EE + lane * 4];
    #pragma unroll
    for (int rr = 0; rr < 8; ++rr) {
        int r = wave * 8 + rr;
        float4 v = *(const float4*)&a[r][lane * 4];
        float p1 = v.x * f1.x + v.y * f1.y + v.z * f1.z + v.w * f1.w;
        float p2 = v.x * f2.x + v.y * f2.y + v.z * f2.z + v.w * f2.w;
        #pragma unroll
        for (int off = 1; off <= 32; off <<= 1) {
            p1 += __shfl_xor(p1, off);
            p2 += __shfl_xor(p2, off);
        }
        if (lane == 0) {
            iefc[row0 + r] = p1;
            ieff[row0 + r] = p2;
        }
    }
}

__global__ __launch_bounds__(NTHR, 4) void k_main(
    const _Float16* __restrict__ ep, const float* __restrict__ yh,
    const _Float16* __restrict__ aW1h, const _Float16* __restrict__ WhhH,
    const float* __restrict__ bias_, const float* __restrict__ ab1,
    const float* __restrict__ aW2, const float* __restrict__ Wih,
    const float* __restrict__ fcW, const float* __restrict__ fcb,
    const float* __restrict__ ffW, const float* __restrict__ ffb,
    const float* __restrict__ iefc, const float* __restrict__ ieff,
    float* __restrict__ out) {
    __shared__ _Float16 s_ep[NB * TT * EE];      // 128 KB: block's ep slice
    __shared__ unsigned int s_hc16[NB][2][128];  // [b][0=h,1=c], f16 pairs
    __shared__ float s_qp[4][NB][EE];            // [kq][b][32*(f&7)+(f>>3)]
    __shared__ float s_sc[NB * TT];
    __shared__ float s_g[NB][4 * DD];            // h.Whh + bias (yt added later)
    __shared__ float s_wih[4 * DD];
    __shared__ float s_iefc[NB][TT];
    __shared__ float s_ieff[NB][TT];
    __shared__ float s_yh[NB][TT];

    const int tid = threadIdx.x;
    const int wave = tid >> 6, lane = tid & 63;
    const int b0 = blockIdx.x * NB;

    // one-time staging
    {
        const uint4* src = (const uint4*)(ep + (size_t)b0 * TT * EE);
        uint4* dst = (uint4*)s_ep;
        #pragma unroll
        for (int i = 0; i < (NB * TT * EE) / 8 / NTHR; ++i)
            dst[tid + i * NTHR] = src[tid + i * NTHR];
    }
    for (int i = tid; i < 4 * DD; i += NTHR) s_wih[i] = Wih[i];
    for (int i = tid; i < NB * TT; i += NTHR) {
        int b = i >> 7, t = i & 127;
        s_iefc[b][t] = iefc[(b0 + b) * TT + t];
        s_ieff[b][t] = ieff[(b0 + b) * TT + t];
        s_yh[b][t]   = yh[(size_t)(b0 + b) * TT + t];
    }
    for (int i = tid; i < NB * 2 * 128; i += NTHR) (&s_hc16[0][0][0])[i] = 0u;

    // ----- q mapping: thread = (kq, qf); kq = K-quarter, both batch rows -----
    const int qf = tid & 255, kq = tid >> 8;     // kq in [0,4)
    const float qinit = (kq == 0) ? ab1[qf] : 0.f;
    const uint4* qW = (const uint4*)aW1h + ((size_t)(kq * 16) * 256 + qf);
    const int qperm = 32 * (qf & 7) + (qf >> 3);
    const int qhc  = kq >> 1;                    // 0 = h-half, 1 = c-half
    const int qoff = (kq & 1) * 64;              // uint index base within row

    // ----- gates mapping: thread = gate row tid (both batch rows) -----
    const uint4* wP = (const uint4*)WhhH + tid;
    const float biasv = bias_[tid];

    // write-once register-resident gate weights: octets 20..31 (k in [160,256))
    const uint4 wr0  = wP[(size_t)20 * 1024];
    const uint4 wr1  = wP[(size_t)21 * 1024];
    const uint4 wr2  = wP[(size_t)22 * 1024];
    const uint4 wr3  = wP[(size_t)23 * 1024];
    const uint4 wr4  = wP[(size_t)24 * 1024];
    const uint4 wr5  = wP[(size_t)25 * 1024];
    const uint4 wr6  = wP[(size_t)26 * 1024];
    const uint4 wr7  = wP[(size_t)27 * 1024];
    const uint4 wr8  = wP[(size_t)28 * 1024];
    const uint4 wr9  = wP[(size_t)29 * 1024];
    const uint4 wr10 = wP[(size_t)30 * 1024];
    const uint4 wr11 = wP[(size_t)31 * 1024];

    // ----- scores mapping -----
    const int l5 = lane & 31;
    const int rsub = wave * 2 + (lane >> 5);     // [0,32)
    const int e0 = l5 * 8;
    float tw2[8]; float sw2 = 0.f;
    #pragma unroll
    for (int j = 0; j < 8; ++j) { float w = aW2[e0 + j]; tw2[j] = 2.f * w; sw2 += w; }

    // ----- softmax/update mapping: wave -> batch row -----
    const int bsm = (wave >> 2) & 1;             // waves 0-3:b0, 4-7:b1 (8-15 redundant)
    const float fcw256 = fcW[256], fcb0 = fcb[0], ffb0 = ffb[0];
    float c_reg = 0.f;                           // fp32 cell state (tid<512)
    float ofs_reg = 0.f;

    __syncthreads();

    for (int t = 0; t < TT; ++t) {
        // ---------- A: q K-quarter (both rows) + gates ----------
        float qa0 = qinit, qa1 = qinit;
        float g0 = biasv, g1 = biasv;
        #pragma unroll
        for (int i = 0; i < 16; ++i) {
            uint4 qwv = qW[(size_t)i * 256];
            uint4 gwv = wP[(size_t)i * 1024];
            uint4 hq0 = *(const uint4*)&s_hc16[0][qhc][qoff + i * 4];
            uint4 hq1 = *(const uint4*)&s_hc16[1][qhc][qoff + i * 4];
            uint4 h0  = *(const uint4*)&s_hc16[0][0][i * 4];
            uint4 h1  = *(const uint4*)&s_hc16[1][0][i * 4];
            qa0 = dot8u4(qwv, hq0, qa0);
            qa1 = dot8u4(qwv, hq1, qa1);
            g0  = dot8u4(gwv, h0, g0);
            g1  = dot8u4(gwv, h1, g1);
        }
        #pragma unroll
        for (int i = 16; i < 20; ++i) {          // gates streamed octets 16..19
            uint4 gwv = wP[(size_t)i * 1024];
            uint4 h0  = *(const uint4*)&s_hc16[0][0][i * 4];
            uint4 h1  = *(const uint4*)&s_hc16[1][0][i * 4];
            g0 = dot8u4(gwv, h0, g0);
            g1 = dot8u4(gwv, h1, g1);
        }
        // gates resident octets 20..31 (straight-line, write-once regs)
        #define GRES(n) { \
            uint4 h0r = *(const uint4*)&s_hc16[0][0][(20 + n) * 4]; \
            uint4 h1r = *(const uint4*)&s_hc16[1][0][(20 + n) * 4]; \
            g0 = dot8u4(wr##n, h0r, g0); \
            g1 = dot8u4(wr##n, h1r, g1); }
        GRES(0) GRES(1) GRES(2) GRES(3) GRES(4) GRES(5)
        GRES(6) GRES(7) GRES(8) GRES(9) GRES(10) GRES(11)
        #undef GRES
        s_qp[kq][0][qperm] = qa0;
        s_qp[kq][1][qperm] = qa1;
        s_g[0][tid] = g0;
        s_g[1][tid] = g1;
        __syncthreads();

        // ---------- B: scores s[b][t'] = sum_f w2[f]*tanh(q+ep+ab1) ----------
        #pragma unroll
        for (int b = 0; b < NB; ++b) {
            float qs[8];
            #pragma unroll
            for (int j = 0; j < 8; ++j) {
                int ix = l5 + 32 * j;
                qs[j] = 2.f * (s_qp[0][b][ix] + s_qp[1][b][ix]
                             + s_qp[2][b][ix] + s_qp[3][b][ix]);
            }
            const _Float16* eph = s_ep + b * TT * EE + e0;
            #pragma unroll
            for (int sw = 0; sw < 4; ++sw) {
                int tt2 = sw * 32 + rsub;
                h8 xv = *(const h8*)(eph + tt2 * EE);
                float s = sw2;
                #pragma unroll
                for (int j = 0; j < 8; ++j) {
                    float e = __expf(__fmaf_rn((float)xv[j], 2.f, qs[j]));
                    s = __fmaf_rn(-tw2[j], __builtin_amdgcn_rcpf(e + 1.f), s);
                }
                #pragma unroll
                for (int off = 1; off <= 16; off <<= 1) s += __shfl_xor(s, off);
                if (l5 == 0) s_sc[b * TT + tt2] = s;
            }
        }
        __syncthreads();

        // ---------- C+D: all-wave shfl softmax + y_tilde + LSTM update ----------
        {
            float v0 = s_sc[bsm * TT + lane], v1 = s_sc[bsm * TT + 64 + lane];
            float m = fmaxf(v0, v1);
            #pragma unroll
            for (int off = 1; off <= 32; off <<= 1) m = fmaxf(m, __shfl_xor(m, off));
            float x0 = __expf(v0 - m), x1 = __expf(v1 - m);
            float ss = x0 + x1;
            #pragma unroll
            for (int off = 1; off <= 32; off <<= 1) ss += __shfl_xor(ss, off);
            float inv = __builtin_amdgcn_rcpf(ss);
            float a0 = x0 * inv, a1 = x1 * inv;
            float p = a0 * s_iefc[bsm][lane] + a1 * s_iefc[bsm][64 + lane];
            #pragma unroll
            for (int off = 1; off <= 32; off <<= 1) p += __shfl_xor(p, off);
            float yt = p + s_yh[bsm][t] * fcw256 + fcb0;
            if (t == TT - 1) {
                float pf = a0 * s_ieff[bsm][lane] + a1 * s_ieff[bsm][64 + lane];
                #pragma unroll
                for (int off = 1; off <= 32; off <<= 1) pf += __shfl_xor(pf, off);
                ofs_reg = pf;
            }
            if (tid < NB * DD) {
                int d = tid & 255;               // batch row = bsm (waves 0-7)
                float gi = s_g[bsm][d]          + yt * s_wih[d];
                float gf = s_g[bsm][DD + d]     + yt * s_wih[DD + d];
                float gg = s_g[bsm][2 * DD + d] + yt * s_wih[2 * DD + d];
                float go = s_g[bsm][3 * DD + d] + yt * s_wih[3 * DD + d];
                float c2 = fsig(gf) * c_reg + fsig(gi) * ftanh(gg);
                c_reg = c2;
                float hn = fsig(go) * ftanh(c2);
                float hO = __shfl_xor(hn, 1);
                float cO = __shfl_xor(c2, 1);
                if (!(d & 1)) {
                    s_hc16[bsm][0][d >> 1] = pkh(hn, hO);
                    s_hc16[bsm][1][d >> 1] = pkh(c2, cO);
                }
            }
        }
        __syncthreads();
    }

    // ---------- final: out[b] = h.ffW[:256] + (attn_last . ieff) + ffb ----------
    if (wave == 0 || wave == 4) {
        int b = wave >> 2;
        unsigned int p0 = s_hc16[b][0][lane * 2];
        unsigned int p1 = s_hc16[b][0][lane * 2 + 1];
        h2 ha = __builtin_bit_cast(h2, p0), hb = __builtin_bit_cast(h2, p1);
        float4 w = *(const float4*)&ffW[lane * 4];
        float p = (float)ha[0] * w.x + (float)ha[1] * w.y
                + (float)hb[0] * w.z + (float)hb[1] * w.w;
        #pragma unroll
        for (int off = 1; off <= 32; off <<= 1) p += __shfl_xor(p, off);
        if (lane == 0) out[b0 + b] = p + ofs_reg + ffb0;
    }
}

extern "C" void kernel_launch(void* const* d_in, const int* in_sizes, int n_in,
                              void* d_out, int out_size, void* d_ws, size_t ws_size,
                              hipStream_t stream) {
    const float* ie  = (const float*)d_in[0];   // [B,T,E]
    const float* yh  = (const float*)d_in[1];   // [B,T,1]
    const float* aW1 = (const float*)d_in[2];   // [768,256]
    const float* ab1 = (const float*)d_in[3];   // [256]
    const float* aW2 = (const float*)d_in[4];   // [256,1]
    // d_in[5] = ab2: additive constant inside softmax -> invariant, unused
    const float* Wih = (const float*)d_in[6];   // [1024,1]
    const float* Whh = (const float*)d_in[7];   // [1024,256]
    const float* bih = (const float*)d_in[8];   // [1024]
    const float* bhh = (const float*)d_in[9];   // [1024]
    const float* fcW = (const float*)d_in[10];  // [1,257]
    const float* fcb = (const float*)d_in[11];  // [1]
    const float* ffW = (const float*)d_in[12];  // [1,512]
    const float* ffb = (const float*)d_in[13];  // [1]
    float* out = (float*)d_out;

    // workspace layout
    _Float16* ep   = (_Float16*)d_ws;                        // 16,777,216 f16 = 32 MiB
    _Float16* aW1h = ep + (size_t)BB * TT * EE;              // 131072 f16
    _Float16* WhhH = aW1h + 512 * EE;                        // 262144 f16
    float* bias = (float*)(WhhH + 262144);                   // 1024 f32
    float* iefc = bias + 1024;                               // 65536 f32
    float* ieff = iefc + BB * TT;                            // 65536 f32

    k_pack<<<1540, 256, 0, stream>>>(aW1, Whh, bih, bhh, aW1h, WhhH, bias);
    k_encproj<<<2048, 256, 0, stream>>>(ie, aW1, fcW, ffW, ep, iefc, ieff);
    k_main<<<BB / NB, NTHR, 0, stream>>>(ep, yh, aW1h, WhhH, bias, ab1, aW2,
                                         Wih, fcW, fcb, ffW, ffb, iefc, ieff, out);
}

// Round 12
// 2927.294 us; speedup vs baseline: 10.1981x; 1.2290x over previous
//
#include <hip/hip_runtime.h>

// DA-RNN decoder: B=512, T=128, E=256, D=256, OUT=1.
// R12: phase-A weights stream L2 -> LDS via async global_load_lds DMA
// (zero data VGPRs -- R8-R11 proved any VGPR-based weight caching spills).
// Wave-private double-buffered 3KB chunks, counted s_waitcnt vmcnt(3),
// no barriers inside phase A. ep streams from L2 in phase B (R4-proven).
// q-GEMM 4-way K-split (weights read once); merged C+D all-wave softmax.
// One 1024-thread block/CU, NB=2 rows, 3 barriers/step.

#define BB 512
#define TT 128
#define EE 256
#define DD 256
#define NB 2
#define NTHR 1024

typedef _Float16 h2 __attribute__((ext_vector_type(2)));
typedef _Float16 h8 __attribute__((ext_vector_type(8)));

#if defined(__has_builtin)
#if __has_builtin(__builtin_amdgcn_fdot2)
#define HAS_FDOT2 1
#endif
#endif

#ifdef HAS_FDOT2
#define FDOT2(a, b, c) __builtin_amdgcn_fdot2(__builtin_bit_cast(h2, (a)), __builtin_bit_cast(h2, (b)), (c), false)
#else
static __device__ __forceinline__ float FDOT2(unsigned int a, unsigned int b, float c) {
    h2 x = __builtin_bit_cast(h2, a), y = __builtin_bit_cast(h2, b);
    return c + (float)x[0] * (float)y[0] + (float)x[1] * (float)y[1];
}
#endif

static __device__ __forceinline__ float dot8u4(uint4 w, uint4 h, float acc) {
    acc = FDOT2(w.x, h.x, acc);
    acc = FDOT2(w.y, h.y, acc);
    acc = FDOT2(w.z, h.z, acc);
    acc = FDOT2(w.w, h.w, acc);
    return acc;
}
static __device__ __forceinline__ unsigned int pkh(float a, float b) {
    union { _Float16 h; unsigned short s; } ua, ub;
    ua.h = (_Float16)a; ub.h = (_Float16)b;
    return (unsigned int)ua.s | ((unsigned int)ub.s << 16);
}
__device__ __forceinline__ float ftanh(float x) {
    return 1.f - 2.f * __builtin_amdgcn_rcpf(__expf(2.f * x) + 1.f);
}
__device__ __forceinline__ float fsig(float x) {
    return __builtin_amdgcn_rcpf(1.f + __expf(-x));
}
// async global->LDS DMA, 16 B per lane: LDS dest = uniform base + lane*16
static __device__ __forceinline__ void gl_lds(const _Float16* g, const uint4* l) {
    __builtin_amdgcn_global_load_lds(
        (const __attribute__((address_space(1))) unsigned int*)g,
        (__attribute__((address_space(3))) unsigned int*)l,
        16, 0, 0);
}

// Pack weights to f16 in the exact load order of k_main.
// aW1h[(g*256+f)*8+j] = aW1[g*8+j][f]      (g<64, k=g*8+j < 512)
// WhhH[(i*1024+jj)*8+m] = Whh[jj][i*8+m]   (i<32)
__global__ __launch_bounds__(256) void k_pack(const float* __restrict__ aW1,
                                              const float* __restrict__ Whh,
                                              const float* __restrict__ bih,
                                              const float* __restrict__ bhh,
                                              _Float16* __restrict__ aW1h,
                                              _Float16* __restrict__ WhhH,
                                              float* __restrict__ bias) {
    int bid = blockIdx.x, tid = threadIdx.x;
    if (bid < 512) {
        int o = bid * 256 + tid;                 // < 131072
        int g = o >> 11, f = (o >> 3) & 255, j = o & 7;
        aW1h[o] = (_Float16)aW1[(g * 8 + j) * EE + f];
    } else if (bid < 1536) {
        int o = (bid - 512) * 256 + tid;         // < 262144
        int i = o >> 13, jj = (o >> 3) & 1023, m = o & 7;
        WhhH[o] = (_Float16)Whh[jj * DD + i * 8 + m];
    } else {
        int j = (bid - 1536) * 256 + tid;        // < 1024
        bias[j] = bih[j] + bhh[j];
    }
}

// ep[n][f] = f16( sum_e ie[n][e]*aW1[512+e][f] )
// epilogue: iefc[n] = dot(ie[n], fcW[0:256]); ieff[n] = dot(ie[n], ffW[256:512])
__global__ __launch_bounds__(256) void k_encproj(const float* __restrict__ ie,
                                                 const float* __restrict__ aW1,
                                                 const float* __restrict__ fcW,
                                                 const float* __restrict__ ffW,
                                                 _Float16* __restrict__ ep,
                                                 float* __restrict__ iefc,
                                                 float* __restrict__ ieff) {
    __shared__ float a[32][EE];
    int row0 = blockIdx.x * 32;
    int tid = threadIdx.x;
    for (int r = 0; r < 32; ++r)
        a[r][tid] = ie[(size_t)(row0 + r) * EE + tid];
    __syncthreads();
    float acc[32];
    #pragma unroll
    for (int r = 0; r < 32; ++r) acc[r] = 0.f;
    const float* wenc = aW1 + 512 * EE;
    for (int e = 0; e < EE; e += 4) {
        float w0 = wenc[(e + 0) * EE + tid];
        float w1 = wenc[(e + 1) * EE + tid];
        float w2 = wenc[(e + 2) * EE + tid];
        float w3 = wenc[(e + 3) * EE + tid];
        #pragma unroll
        for (int r = 0; r < 32; ++r) {
            float4 av = *(const float4*)&a[r][e];
            acc[r] += av.x * w0 + av.y * w1 + av.z * w2 + av.w * w3;
        }
    }
    for (int r = 0; r < 32; ++r)
        ep[(size_t)(row0 + r) * EE + tid] = (_Float16)acc[r];

    int wave = tid >> 6, lane = tid & 63;
    float4 f1 = *(const float4*)&fcW[lane * 4];
    float4 f2 = *(const float4*)&ffW[EE + lane * 4];
    #pragma unroll
    for (int rr = 0; rr < 8; ++rr) {
        int r = wave * 8 + rr;
        float4 v = *(const float4*)&a[r][lane * 4];
        float p1 = v.x * f1.x + v.y * f1.y + v.z * f1.z + v.w * f1.w;
        float p2 = v.x * f2.x + v.y * f2.y + v.z * f2.z + v.w * f2.w;
        #pragma unroll
        for (int off = 1; off <= 32; off <<= 1) {
            p1 += __shfl_xor(p1, off);
            p2 += __shfl_xor(p2, off);
        }
        if (lane == 0) {
            iefc[row0 + r] = p1;
            ieff[row0 + r] = p2;
        }
    }
}

__global__ __launch_bounds__(NTHR) void k_main(
    const _Float16* __restrict__ ep, const float* __restrict__ yh,
    const _Float16* __restrict__ aW1h, const _Float16* __restrict__ WhhH,
    const float* __restrict__ bias_, const float* __restrict__ ab1,
    const float* __restrict__ aW2, const float* __restrict__ Wih,
    const float* __restrict__ fcW, const float* __restrict__ fcb,
    const float* __restrict__ ffW, const float* __restrict__ ffb,
    const float* __restrict__ iefc, const float* __restrict__ ieff,
    float* __restrict__ out) {
    __shared__ uint4 s_wbuf[16][2][3][64];       // 96 KB wave-private DMA bufs
    __shared__ unsigned int s_hc16[NB][2][128];  // [b][0=h,1=c], f16 pairs
    __shared__ float s_qp[4][NB][EE];            // [kq][b][32*(f&7)+(f>>3)]
    __shared__ float s_sc[NB * TT];
    __shared__ float s_g[NB][4 * DD];            // h.Whh + bias (yt added later)
    __shared__ float s_wih[4 * DD];
    __shared__ float s_iefc[NB][TT];
    __shared__ float s_ieff[NB][TT];
    __shared__ float s_yh[NB][TT];

    const int tid = threadIdx.x;
    const int wave = tid >> 6, lane = tid & 63;
    const int b0 = blockIdx.x * NB;

    for (int i = tid; i < 4 * DD; i += NTHR) s_wih[i] = Wih[i];
    for (int i = tid; i < NB * TT; i += NTHR) {
        int b = i >> 7, t = i & 127;
        s_iefc[b][t] = iefc[(b0 + b) * TT + t];
        s_ieff[b][t] = ieff[(b0 + b) * TT + t];
        s_yh[b][t]   = yh[(size_t)(b0 + b) * TT + t];
    }
    for (int i = tid; i < NB * 2 * 128; i += NTHR) (&s_hc16[0][0][0])[i] = 0u;

    // ----- q mapping: thread = (kq, qf); kq = K-quarter, both batch rows -----
    const int qf = tid & 255, kq = tid >> 8;     // kq in [0,4)
    const float qinit = (kq == 0) ? ab1[qf] : 0.f;
    const int qperm = 32 * (qf & 7) + (qf >> 3);
    const int qhc  = kq >> 1;                    // 0 = h-half, 1 = c-half
    const int qoff = (kq & 1) * 64;              // uint index base within row

    // per-lane global weight source addresses (f16 elements)
    const _Float16* gsrcG = WhhH + (size_t)tid * 8;                       // + octet*8192
    const _Float16* gsrcQ = aW1h + ((size_t)(kq * 16) * 256 + qf) * 8;    // + c*2048
    const float biasv = bias_[tid];

    // ----- scores mapping -----
    const int l5 = lane & 31;
    const int rsub = wave * 2 + (lane >> 5);     // [0,32)
    const int e0 = l5 * 8;
    float tw2[8]; float sw2 = 0.f;
    #pragma unroll
    for (int j = 0; j < 8; ++j) { float w = aW2[e0 + j]; tw2[j] = 2.f * w; sw2 += w; }

    // ----- softmax/update mapping: wave -> batch row -----
    const int bsm = (wave >> 2) & 1;             // waves 0-3:b0, 4-7:b1 (8-15 redundant)
    const float fcw256 = fcW[256], fcb0 = fcb[0], ffb0 = ffb[0];
    float c_reg = 0.f;                           // fp32 cell state (tid<512)
    float ofs_reg = 0.f;

    // issue chunk c into wave-private buffer p: {gate octet 2c, 2c+1, q octet c}
    #define ISSUE(c, p) do { \
        gl_lds(gsrcG + (size_t)(2 * (c)) * 8192,     &s_wbuf[wave][p][0][0]); \
        gl_lds(gsrcG + (size_t)(2 * (c) + 1) * 8192, &s_wbuf[wave][p][1][0]); \
        gl_lds(gsrcQ + (size_t)(c) * 2048,           &s_wbuf[wave][p][2][0]); \
    } while (0)

    ISSUE(0, 0);                                 // prologue prefetch
    __syncthreads();

    for (int t = 0; t < TT; ++t) {
        // ---------- A: wave-private DMA-pipelined q + gates GEMMs ----------
        float qa0 = qinit, qa1 = qinit;
        float g0 = biasv, g1 = biasv;
        #pragma unroll
        for (int c = 0; c < 16; ++c) {
            const int p = c & 1;
            if (c < 15) {
                ISSUE(c + 1, (c + 1) & 1);
                asm volatile("s_waitcnt vmcnt(3)" ::: "memory");
            } else {
                asm volatile("s_waitcnt vmcnt(0)" ::: "memory");
            }
            uint4 gw0 = s_wbuf[wave][p][0][lane];
            uint4 gw1 = s_wbuf[wave][p][1][lane];
            uint4 qw  = s_wbuf[wave][p][2][lane];
            const int o0 = 2 * c, o1 = 2 * c + 1;
            uint4 h00 = *(const uint4*)&s_hc16[0][0][o0 * 4];
            uint4 h10 = *(const uint4*)&s_hc16[1][0][o0 * 4];
            uint4 h01 = *(const uint4*)&s_hc16[0][0][o1 * 4];
            uint4 h11 = *(const uint4*)&s_hc16[1][0][o1 * 4];
            uint4 hq0 = *(const uint4*)&s_hc16[0][qhc][qoff + c * 4];
            uint4 hq1 = *(const uint4*)&s_hc16[1][qhc][qoff + c * 4];
            g0 = dot8u4(gw0, h00, g0);
            g1 = dot8u4(gw0, h10, g1);
            g0 = dot8u4(gw1, h01, g0);
            g1 = dot8u4(gw1, h11, g1);
            qa0 = dot8u4(qw, hq0, qa0);
            qa1 = dot8u4(qw, hq1, qa1);
        }
        ISSUE(0, 0);                             // prefetch chunk 0 of next step
        s_qp[kq][0][qperm] = qa0;
        s_qp[kq][1][qperm] = qa1;
        s_g[0][tid] = g0;
        s_g[1][tid] = g1;
        __syncthreads();

        // ---------- B: scores from GLOBAL ep (L2-resident) ----------
        #pragma unroll
        for (int b = 0; b < NB; ++b) {
            float qs[8];
            #pragma unroll
            for (int j = 0; j < 8; ++j) {
                int ix = l5 + 32 * j;
                qs[j] = 2.f * (s_qp[0][b][ix] + s_qp[1][b][ix]
                             + s_qp[2][b][ix] + s_qp[3][b][ix]);
            }
            const _Float16* eph = ep + (size_t)(b0 + b) * TT * EE + e0;
            #pragma unroll
            for (int sw = 0; sw < 4; ++sw) {
                int tt2 = sw * 32 + rsub;
                h8 xv = *(const h8*)(eph + (size_t)tt2 * EE);
                float s = sw2;
                #pragma unroll
                for (int j = 0; j < 8; ++j) {
                    float e = __expf(__fmaf_rn((float)xv[j], 2.f, qs[j]));
                    s = __fmaf_rn(-tw2[j], __builtin_amdgcn_rcpf(e + 1.f), s);
                }
                #pragma unroll
                for (int off = 1; off <= 16; off <<= 1) s += __shfl_xor(s, off);
                if (l5 == 0) s_sc[b * TT + tt2] = s;
            }
        }
        __syncthreads();

        // ---------- C+D: all-wave shfl softmax + y_tilde + LSTM update ----------
        {
            float v0 = s_sc[bsm * TT + lane], v1 = s_sc[bsm * TT + 64 + lane];
            float m = fmaxf(v0, v1);
            #pragma unroll
            for (int off = 1; off <= 32; off <<= 1) m = fmaxf(m, __shfl_xor(m, off));
            float x0 = __expf(v0 - m), x1 = __expf(v1 - m);
            float ss = x0 + x1;
            #pragma unroll
            for (int off = 1; off <= 32; off <<= 1) ss += __shfl_xor(ss, off);
            float inv = __builtin_amdgcn_rcpf(ss);
            float a0 = x0 * inv, a1 = x1 * inv;
            float p = a0 * s_iefc[bsm][lane] + a1 * s_iefc[bsm][64 + lane];
            #pragma unroll
            for (int off = 1; off <= 32; off <<= 1) p += __shfl_xor(p, off);
            float yt = p + s_yh[bsm][t] * fcw256 + fcb0;
            if (t == TT - 1) {
                float pf = a0 * s_ieff[bsm][lane] + a1 * s_ieff[bsm][64 + lane];
                #pragma unroll
                for (int off = 1; off <= 32; off <<= 1) pf += __shfl_xor(pf, off);
                ofs_reg = pf;
            }
            if (tid < NB * DD) {
                int d = tid & 255;               // batch row = bsm (waves 0-7)
                float gi = s_g[bsm][d]          + yt * s_wih[d];
                float gf = s_g[bsm][DD + d]     + yt * s_wih[DD + d];
                float gg = s_g[bsm][2 * DD + d] + yt * s_wih[2 * DD + d];
                float go = s_g[bsm][3 * DD + d] + yt * s_wih[3 * DD + d];
                float c2 = fsig(gf) * c_reg + fsig(gi) * ftanh(gg);
                c_reg = c2;
                float hn = fsig(go) * ftanh(c2);
                float hO = __shfl_xor(hn, 1);
                float cO = __shfl_xor(c2, 1);
                if (!(d & 1)) {
                    s_hc16[bsm][0][d >> 1] = pkh(hn, hO);
                    s_hc16[bsm][1][d >> 1] = pkh(c2, cO);
                }
            }
        }
        __syncthreads();
    }
    #undef ISSUE

    // ---------- final: out[b] = h.ffW[:256] + (attn_last . ieff) + ffb ----------
    if (wave == 0 || wave == 4) {
        int b = wave >> 2;
        unsigned int p0 = s_hc16[b][0][lane * 2];
        unsigned int p1 = s_hc16[b][0][lane * 2 + 1];
        h2 ha = __builtin_bit_cast(h2, p0), hb = __builtin_bit_cast(h2, p1);
        float4 w = *(const float4*)&ffW[lane * 4];
        float p = (float)ha[0] * w.x + (float)ha[1] * w.y
                + (float)hb[0] * w.z + (float)hb[1] * w.w;
        #pragma unroll
        for (int off = 1; off <= 32; off <<= 1) p += __shfl_xor(p, off);
        if (lane == 0) out[b0 + b] = p + ofs_reg + ffb0;
    }
}

extern "C" void kernel_launch(void* const* d_in, const int* in_sizes, int n_in,
                              void* d_out, int out_size, void* d_ws, size_t ws_size,
                              hipStream_t stream) {
    const float* ie  = (const float*)d_in[0];   // [B,T,E]
    const float* yh  = (const float*)d_in[1];   // [B,T,1]
    const float* aW1 = (const float*)d_in[2];   // [768,256]
    const float* ab1 = (const float*)d_in[3];   // [256]
    const float* aW2 = (const float*)d_in[4];   // [256,1]
    // d_in[5] = ab2: additive constant inside softmax -> invariant, unused
    const float* Wih = (const float*)d_in[6];   // [1024,1]
    const float* Whh = (const float*)d_in[7];   // [1024,256]
    const float* bih = (const float*)d_in[8];   // [1024]
    const float* bhh = (const float*)d_in[9];   // [1024]
    const float* fcW = (const float*)d_in[10];  // [1,257]
    const float* fcb = (const float*)d_in[11];  // [1]
    const float* ffW = (const float*)d_in[12];  // [1,512]
    const float* ffb = (const float*)d_in[13];  // [1]
    float* out = (float*)d_out;

    // workspace layout
    _Float16* ep   = (_Float16*)d_ws;                        // 16,777,216 f16 = 32 MiB
    _Float16* aW1h = ep + (size_t)BB * TT * EE;              // 131072 f16
    _Float16* WhhH = aW1h + 512 * EE;                        // 262144 f16
    float* bias = (float*)(WhhH + 262144);                   // 1024 f32
    float* iefc = bias + 1024;                               // 65536 f32
    float* ieff = iefc + BB * TT;                            // 65536 f32

    k_pack<<<1540, 256, 0, stream>>>(aW1, Whh, bih, bhh, aW1h, WhhH, bias);
    k_encproj<<<2048, 256, 0, stream>>>(ie, aW1, fcW, ffW, ep, iefc, ieff);
    k_main<<<BB / NB, NTHR, 0, stream>>>(ep, yh, aW1h, WhhH, bias, ab1, aW2,
                                         Wih, fcW, fcb, ffW, ffb, iefc, ieff, out);
}